// Round 1
// baseline (113.361 us; speedup 1.0000x reference)
//
#include <hip/hip_runtime.h>

#define NBATCH 4096
#define NT 2048
#define NP 1024
#define NTH 256
#define EPT 8   // NT elements per thread
#define PPT 4   // NP elements per thread
#define MSZ 1022          // interior system size (NP-2)
#define KTRUNC 25         // convolution half-width: |rho|^25 ~ 1e-14
#define IMGW 40           // boundary image reach

__global__ __launch_bounds__(NTH) void w2loss_kernel(
    const float* __restrict__ f,
    const float* __restrict__ obs,
    float* __restrict__ out)
{
    __shared__ float sP[NT];      // inclusive prefix of squares
    __shared__ float sC[NT];      // cdf (phase A) / F (phase B)
    __shared__ float sQ[NP];      // q = t[idx]
    __shared__ float sR[NP];      // rhs
    __shared__ float sM[NP];      // second-derivative M
    __shared__ float sScan[NTH];
    __shared__ float sPow[IMGW]; // rho^d
    __shared__ float sT[2];       // image sums T1, T2
    __shared__ float sRed[NTH / 64];

    const int b   = blockIdx.x;
    const int tid = threadIdx.x;

    const float dt      = 0.001f;
    const float half_dt = 0.5f * dt;
    const float h       = 1.0f / 1023.0f;
    const float inv_h   = 1023.0f;
    const float inv_h2  = inv_h * inv_h;

    // rho^d table (rho = sqrt(3)-2, negative)
    if (tid < IMGW) {
        const float rho = -0.26794919243112270647f;
        float v = 1.0f;
        for (int i = 0; i < tid; ++i) v *= rho;
        sPow[tid] = v;
    }

    // ---------------- Phase A: obs -> cdf ----------------
    const float* orow = obs + (size_t)b * NT;
    float sq[EPT];
    {
        const int base = tid * EPT;
        float4 v0 = *reinterpret_cast<const float4*>(orow + base);
        float4 v1 = *reinterpret_cast<const float4*>(orow + base + 4);
        sq[0] = v0.x * v0.x; sq[1] = v0.y * v0.y; sq[2] = v0.z * v0.z; sq[3] = v0.w * v0.w;
        sq[4] = v1.x * v1.x; sq[5] = v1.y * v1.y; sq[6] = v1.z * v1.z; sq[7] = v1.w * v1.w;
    }
    float pref[EPT];
    pref[0] = sq[0];
#pragma unroll
    for (int e = 1; e < EPT; ++e) pref[e] = pref[e - 1] + sq[e];
    float tsum = pref[EPT - 1];
    sScan[tid] = tsum;
    __syncthreads();
#pragma unroll
    for (int off = 1; off < NTH; off <<= 1) {
        float v = (tid >= off) ? sScan[tid - off] : 0.0f;
        __syncthreads();
        sScan[tid] += v;
        __syncthreads();
    }
    {
        float excl = sScan[tid] - tsum;
#pragma unroll
        for (int e = 0; e < EPT; ++e) sP[tid * EPT + e] = pref[e] + excl;
    }
    __syncthreads();

    {
        float sq0  = sP[0];
        float S    = half_dt * (sP[NT - 2] + sP[NT - 1] - sq0);
        float invS = 1.0f / S;
#pragma unroll
        for (int e = 0; e < EPT; ++e) {
            int j = tid * EPT + e;
            sC[j] = (j == 0) ? 0.0f : half_dt * (sP[j - 1] + sP[j] - sq0) * invS;
        }
    }
    __syncthreads();

    // inverse-CDF sample: lower_bound(cdf, p_k)
#pragma unroll
    for (int kk = 0; kk < PPT; ++kk) {
        int k = tid + kk * NTH;
        float pk = (k == NP - 1) ? 1.0f : (float)k * h;
        int lo = 0, hi = NT;
        while (lo < hi) {
            int mid = (lo + hi) >> 1;
            if (sC[mid] < pk) lo = mid + 1; else hi = mid;
        }
        int idx = lo > (NT - 1) ? (NT - 1) : lo;
        sQ[k] = (float)idx * dt;
    }
    __syncthreads();

    // rhs_i = 6*(q_i - 2 q_{i+1} + q_{i+2})/h^2
#pragma unroll
    for (int kk = 0; kk < PPT; ++kk) {
        int i = tid + kk * NTH;
        if (i < MSZ)
            sR[i] = 6.0f * (sQ[i] - 2.0f * sQ[i + 1] + sQ[i + 2]) * inv_h2;
    }
    __syncthreads();

    // boundary image sums
    if (tid == 0) {
        float t1 = 0.0f;
        for (int k = 0; k < IMGW - 1; ++k) t1 += sPow[k + 1] * sR[k];
        sT[0] = t1;
    } else if (tid == 64) {
        float t2 = 0.0f;
        for (int k = MSZ - (IMGW - 1); k < MSZ; ++k) t2 += sPow[MSZ - k] * sR[k];
        sT[1] = t2;
    }
    __syncthreads();

    // tridiagonal solve via truncated Green's-function convolution + images
    {
        const float Cg = 0.28867513459481288225f; // 1/(2*sqrt(3))
        float T1 = sT[0], T2 = sT[1];
#pragma unroll
        for (int kk = 0; kk < PPT; ++kk) {
            int i = tid + kk * NTH;
            if (i < MSZ) {
                int lo = i - KTRUNC; if (lo < 0) lo = 0;
                int hi = i + KTRUNC; if (hi > MSZ - 1) hi = MSZ - 1;
                float acc = 0.0f;
                for (int k = lo; k <= hi; ++k) {
                    int d = i - k; if (d < 0) d = -d;
                    acc += sPow[d] * sR[k];
                }
                if (i + 1 < IMGW)   acc -= sPow[i + 1] * T1;
                if (MSZ - i < IMGW) acc -= sPow[MSZ - i] * T2;
                sM[i + 1] = Cg * acc;
            }
        }
    }
    if (tid == 0) { sM[0] = 0.0f; sM[NP - 1] = 0.0f; }
    __syncthreads();

    // ---------------- Phase B: f -> F, evaluate, integrate ----------------
    const float* frow = f + (size_t)b * NT;
    {
        const int base = tid * EPT;
        float4 v0 = *reinterpret_cast<const float4*>(frow + base);
        float4 v1 = *reinterpret_cast<const float4*>(frow + base + 4);
        sq[0] = v0.x * v0.x; sq[1] = v0.y * v0.y; sq[2] = v0.z * v0.z; sq[3] = v0.w * v0.w;
        sq[4] = v1.x * v1.x; sq[5] = v1.y * v1.y; sq[6] = v1.z * v1.z; sq[7] = v1.w * v1.w;
    }
    pref[0] = sq[0];
#pragma unroll
    for (int e = 1; e < EPT; ++e) pref[e] = pref[e - 1] + sq[e];
    tsum = pref[EPT - 1];
    sScan[tid] = tsum;
    __syncthreads();
#pragma unroll
    for (int off = 1; off < NTH; off <<= 1) {
        float v = (tid >= off) ? sScan[tid - off] : 0.0f;
        __syncthreads();
        sScan[tid] += v;
        __syncthreads();
    }
    {
        float excl = sScan[tid] - tsum;
#pragma unroll
        for (int e = 0; e < EPT; ++e) sP[tid * EPT + e] = pref[e] + excl;
    }
    __syncthreads();

    float sq0f  = sP[0];
    float Sf    = half_dt * (sP[NT - 2] + sP[NT - 1] - sq0f);
    float invSf = 1.0f / Sf;
#pragma unroll
    for (int e = 0; e < EPT; ++e) {
        int j = tid * EPT + e;
        sC[j] = (j == 0) ? 0.0f : half_dt * (sP[j - 1] + sP[j] - sq0f) * invSf;
    }
    __syncthreads();

    float local = 0.0f;
#pragma unroll
    for (int e = 0; e < EPT; ++e) {
        int j = tid * EPT + e;
        float Fj = sC[j];
        float ft = sq[e] * invSf;
        int k = (int)floorf(Fj * inv_h);
        if (k < 0) k = 0;
        if (k > NP - 2) k = NP - 2;
        float pk  = (float)k * h;
        float s   = Fj - pk;
        float qk  = sQ[k], qk1 = sQ[k + 1];
        float Mk  = sM[k], Mk1 = sM[k + 1];
        float bco = (qk1 - qk) * inv_h - h * (2.0f * Mk + Mk1) * (1.0f / 6.0f);
        float cco = 0.5f * Mk;
        float dco = (Mk1 - Mk) * (inv_h * (1.0f / 6.0f));
        float od  = qk + s * (bco + s * (cco + s * dco));
        float tj  = (float)j * dt;
        float dd  = tj - od;
        float w   = (j == 0 || j == NT - 1) ? half_dt : dt;
        local += dd * dd * ft * w;
    }

    // block reduce + global atomic
#pragma unroll
    for (int off = 32; off > 0; off >>= 1) local += __shfl_down(local, off);
    if ((tid & 63) == 0) sRed[tid >> 6] = local;
    __syncthreads();
    if (tid == 0) {
        float tot = sRed[0] + sRed[1] + sRed[2] + sRed[3];
        atomicAdd(out, tot);
    }
}

extern "C" void kernel_launch(void* const* d_in, const int* in_sizes, int n_in,
                              void* d_out, int out_size, void* d_ws, size_t ws_size,
                              hipStream_t stream) {
    const float* f   = (const float*)d_in[0];
    const float* obs = (const float*)d_in[1];
    float* out = (float*)d_out;

    hipMemsetAsync(out, 0, sizeof(float), stream);
    w2loss_kernel<<<NBATCH, NTH, 0, stream>>>(f, obs, out);
}

// Round 2
// 70.465 us; speedup vs baseline: 1.6087x; 1.6087x over previous
//
#include <hip/hip_runtime.h>

#define NBATCH 4096
#define NT 2048
#define NP 1024
#define NTH 256
#define EPT 8   // NT elements per thread
#define PPT 4   // NP elements per thread
#define MSZ 1022          // interior system size (NP-2)
#define KT 12             // conv half-width: |rho|^13 ~ 3.7e-8 (f32-negligible)
#define IMGW 14           // boundary image reach

__device__ __forceinline__ int padi(int j) { return j + (j >> 3); }

__global__ __launch_bounds__(NTH) void w2loss_kernel(
    const float* __restrict__ f,
    const float* __restrict__ obs,
    float* __restrict__ out)
{
    __shared__ float  sC[2304];          // padded cdf (phase A only)
    __shared__ float2 sQM[NP];           // .x = q_k, .y = M_k
    __shared__ float  sRp[MSZ + 2 * KT]; // zero-padded rhs
    __shared__ float  sPow[IMGW];        // rho^d (runtime-indexed uses)
    __shared__ float  sWS[4];
    __shared__ float  sT[2];
    __shared__ float  sSq[2];
    __shared__ float  sRed[4];

    const int tid  = threadIdx.x;
    const int lane = tid & 63;
    const int wid  = tid >> 6;
    const int b    = blockIdx.x;
    const int base = tid * EPT;

    const float dt      = 0.001f;
    const float half_dt = 0.0005f;
    const float h       = 0.00097751710654936461f;  // 1/1023
    const float inv_h   = 1023.0f;
    const float inv_h2  = 1046529.0f;               // 1023^2

    // prefetch both rows up front (f sits in regs through phase A)
    const float* orow = obs + (size_t)b * NT;
    const float* frow = f   + (size_t)b * NT;
    float4 o0 = *reinterpret_cast<const float4*>(orow + base);
    float4 o1 = *reinterpret_cast<const float4*>(orow + base + 4);
    float4 g0 = *reinterpret_cast<const float4*>(frow + base);
    float4 g1 = *reinterpret_cast<const float4*>(frow + base + 4);

    if (tid < IMGW) {
        const float rho = -0.26794919243112270f;
        float v = 1.0f;
        for (int i = 0; i < tid; ++i) v *= rho;
        sPow[tid] = v;
    }

    // ---------------- Phase A: obs -> cdf (registers + wave scan) ----------------
    float sq[EPT], pref[EPT];
    sq[0]=o0.x*o0.x; sq[1]=o0.y*o0.y; sq[2]=o0.z*o0.z; sq[3]=o0.w*o0.w;
    sq[4]=o1.x*o1.x; sq[5]=o1.y*o1.y; sq[6]=o1.z*o1.z; sq[7]=o1.w*o1.w;
    pref[0] = sq[0];
#pragma unroll
    for (int e = 1; e < EPT; ++e) pref[e] = pref[e - 1] + sq[e];
    float tsum = pref[EPT - 1];
    float ws = tsum;
#pragma unroll
    for (int off = 1; off < 64; off <<= 1) {
        float u = __shfl_up(ws, off);
        if (lane >= off) ws += u;
    }
    if (lane == 63) sWS[wid] = ws;
    if (tid == 0) sSq[0] = sq[0];
    if (tid == NTH - 1) sSq[1] = sq[EPT - 1];
    __syncthreads();

    float excl = ws - tsum;
    if (wid > 0) excl += sWS[0];
    if (wid > 1) excl += sWS[1];
    if (wid > 2) excl += sWS[2];
    float total = sWS[0] + sWS[1] + sWS[2] + sWS[3];
    float sq0 = sSq[0], sqL = sSq[1];
    float invS = 1.0f / (half_dt * (2.0f * total - sqL - sq0));

#pragma unroll
    for (int e = 0; e < EPT; ++e) {
        int j = base + e;
        float Pm1 = excl + (e ? pref[e - 1] : 0.0f);
        float c = (j == 0) ? 0.0f : half_dt * (Pm1 + excl + pref[e] - sq0) * invS;
        sC[padi(j)] = c;
    }
    __syncthreads();

    // ---------------- inverse-CDF sample (branchless power-of-2 lower_bound) ----------------
#pragma unroll
    for (int kk = 0; kk < PPT; ++kk) {
        int k = tid + kk * NTH;
        float pk = (k == NP - 1) ? 1.0f : (float)k * h;
        int pos = 0;
#pragma unroll
        for (int step = 1024; step > 0; step >>= 1) {
            int np_ = pos + step;
            if (sC[padi(np_ - 1)] < pk) pos = np_;
        }
        int idx = pos > (NT - 1) ? (NT - 1) : pos;
        sQM[k].x = (float)idx * dt;
    }
    __syncthreads();

    // ---------------- rhs (zero-padded) ----------------
#pragma unroll
    for (int kk = 0; kk < PPT; ++kk) {
        int i = tid + kk * NTH;
        if (i < MSZ)
            sRp[KT + i] = 6.0f * (sQM[i].x - 2.0f * sQM[i + 1].x + sQM[i + 2].x) * inv_h2;
    }
    if (tid < KT) sRp[tid] = 0.0f;
    else if (tid < 2 * KT) sRp[KT + MSZ + tid - KT] = 0.0f;
    __syncthreads();

    // boundary image sums
    if (tid == 0) {
        float t1 = 0.0f;
#pragma unroll
        for (int k = 0; k < IMGW - 1; ++k) t1 += sPow[k + 1] * sRp[KT + k];
        sT[0] = t1;
    } else if (tid == 64) {
        float t2 = 0.0f;
#pragma unroll
        for (int k = MSZ - IMGW + 1; k < MSZ; ++k) t2 += sPow[MSZ - k] * sRp[KT + k];
        sT[1] = t2;
    }
    __syncthreads();

    // ---------------- tridiagonal solve: constant-tap convolution + images ----------------
    {
        const float Cg = 0.28867513459481288f; // 1/(2*sqrt(3))
        const float CP[KT + 1] = {
            1.0f, -0.26794919243112270f, 0.071796769724490830f,
            -0.019237886466840f, 0.0051547761428900f, -0.0013812184000f,
            0.00037009627600f, -9.9166997e-05f, 2.6571322e-05f,
            -7.1197520e-06f, 1.9076502e-06f, -5.1115295e-07f, 1.3696300e-07f };
        float T1 = sT[0], T2 = sT[1];
#pragma unroll
        for (int kk = 0; kk < PPT; ++kk) {
            int i = tid + kk * NTH;
            if (i < MSZ) {
                float acc = 0.0f;
#pragma unroll
                for (int d = -KT; d <= KT; ++d) {
                    int ad = d < 0 ? -d : d;
                    acc += CP[ad] * sRp[KT + i + d];
                }
                if (i + 1 < IMGW)    acc -= sPow[i + 1] * T1;
                if (MSZ - i < IMGW)  acc -= sPow[MSZ - i] * T2;
                sQM[i + 1].y = Cg * acc;
            }
        }
    }
    if (tid == 0) { sQM[0].y = 0.0f; sQM[NP - 1].y = 0.0f; }
    __syncthreads();

    // ---------------- Phase B: f -> F in registers, evaluate, integrate ----------------
    sq[0]=g0.x*g0.x; sq[1]=g0.y*g0.y; sq[2]=g0.z*g0.z; sq[3]=g0.w*g0.w;
    sq[4]=g1.x*g1.x; sq[5]=g1.y*g1.y; sq[6]=g1.z*g1.z; sq[7]=g1.w*g1.w;
    pref[0] = sq[0];
#pragma unroll
    for (int e = 1; e < EPT; ++e) pref[e] = pref[e - 1] + sq[e];
    tsum = pref[EPT - 1];
    ws = tsum;
#pragma unroll
    for (int off = 1; off < 64; off <<= 1) {
        float u = __shfl_up(ws, off);
        if (lane >= off) ws += u;
    }
    if (lane == 63) sWS[wid] = ws;
    if (tid == 0) sSq[0] = sq[0];
    if (tid == NTH - 1) sSq[1] = sq[EPT - 1];
    __syncthreads();

    excl = ws - tsum;
    if (wid > 0) excl += sWS[0];
    if (wid > 1) excl += sWS[1];
    if (wid > 2) excl += sWS[2];
    total = sWS[0] + sWS[1] + sWS[2] + sWS[3];
    float sq0f = sSq[0], sqLf = sSq[1];
    float invSf = 1.0f / (half_dt * (2.0f * total - sqLf - sq0f));

    float local = 0.0f;
#pragma unroll
    for (int e = 0; e < EPT; ++e) {
        int j = base + e;
        float Pm1 = excl + (e ? pref[e - 1] : 0.0f);
        float Fj = (j == 0) ? 0.0f : half_dt * (Pm1 + excl + pref[e] - sq0f) * invSf;
        float ft = sq[e] * invSf;
        int k = (int)(Fj * inv_h);
        if (k < 0) k = 0;
        if (k > NP - 2) k = NP - 2;
        float s = Fj - (float)k * h;
        float2 qm0 = sQM[k];
        float2 qm1 = sQM[k + 1];
        float bco = (qm1.x - qm0.x) * inv_h - h * (2.0f * qm0.y + qm1.y) * (1.0f / 6.0f);
        float cco = 0.5f * qm0.y;
        float dco = (qm1.y - qm0.y) * (inv_h * (1.0f / 6.0f));
        float od  = qm0.x + s * (bco + s * (cco + s * dco));
        float tj  = (float)j * dt;
        float dd  = tj - od;
        float w   = (j == 0 || j == NT - 1) ? half_dt : dt;
        local += dd * dd * ft * w;
    }

#pragma unroll
    for (int off = 32; off > 0; off >>= 1) local += __shfl_down(local, off);
    if (lane == 0) sRed[wid] = local;
    __syncthreads();
    if (tid == 0) atomicAdd(out, sRed[0] + sRed[1] + sRed[2] + sRed[3]);
}

extern "C" void kernel_launch(void* const* d_in, const int* in_sizes, int n_in,
                              void* d_out, int out_size, void* d_ws, size_t ws_size,
                              hipStream_t stream) {
    const float* f   = (const float*)d_in[0];
    const float* obs = (const float*)d_in[1];
    float* out = (float*)d_out;

    hipMemsetAsync(out, 0, sizeof(float), stream);
    w2loss_kernel<<<NBATCH, NTH, 0, stream>>>(f, obs, out);
}

// Round 3
// 67.556 us; speedup vs baseline: 1.6780x; 1.0431x over previous
//
#include <hip/hip_runtime.h>

#define NBATCH 4096
#define NT 2048
#define NP 1024
#define NTH 256
#define EPT 8   // NT elements per thread
#define PPT 4   // NP items per thread
#define MSZ 1022          // interior system size (NP-2)
#define KT 6              // conv half-width: |rho|^7 ~ 1e-4, scaled by h^2/6 -> ~1e-10 in spline
#define IMGW 14           // boundary image reach

__global__ __launch_bounds__(NTH, 8) void w2loss_kernel(
    const float* __restrict__ f,
    const float* __restrict__ obs,
    float* __restrict__ out)
{
    __shared__ float2 sQM[NP];           // .x = q_k, .y = M_k
    __shared__ float  sRp[MSZ + 2 * KT]; // zero-padded rhs
    __shared__ float  sCB[NTH];          // per-thread boundary cdf (c at j=base+7)
    __shared__ float  sPow[IMGW];        // rho^d
    __shared__ float  sWSA[4], sWSB[4];
    __shared__ float  sSqA[2], sSqB[2];
    __shared__ float  sRed[4];

    const int tid  = threadIdx.x;
    const int lane = tid & 63;
    const int wid  = tid >> 6;
    const int b    = blockIdx.x;
    const int base = tid * EPT;

    const float dt      = 0.001f;
    const float half_dt = 0.0005f;
    const float h       = 0.00097751710654936461f;  // 1/1023
    const float inv_h   = 1023.0f;
    const float inv_h2  = 1046529.0f;               // 1023^2

    const float* orow = obs + (size_t)b * NT;
    const float* frow = f   + (size_t)b * NT;
    float4 o0 = *reinterpret_cast<const float4*>(orow + base);
    float4 o1 = *reinterpret_cast<const float4*>(orow + base + 4);
    float4 g0 = *reinterpret_cast<const float4*>(frow + base);
    float4 g1 = *reinterpret_cast<const float4*>(frow + base + 4);

    if (tid < IMGW) {
        const float rho = -0.26794919243112270f;
        float v = 1.0f;
        for (int i = 0; i < tid; ++i) v *= rho;
        sPow[tid] = v;
    }
    if (tid < KT) { sRp[tid] = 0.0f; sRp[KT + MSZ + tid] = 0.0f; }

    // ---- squares + per-thread prefixes for BOTH rows ----
    float prefA[EPT], prefB[EPT];
    {
        float s0;
        s0 = o0.x*o0.x; prefA[0] = s0;
        s0 = o0.y*o0.y; prefA[1] = prefA[0] + s0;
        s0 = o0.z*o0.z; prefA[2] = prefA[1] + s0;
        s0 = o0.w*o0.w; prefA[3] = prefA[2] + s0;
        s0 = o1.x*o1.x; prefA[4] = prefA[3] + s0;
        s0 = o1.y*o1.y; prefA[5] = prefA[4] + s0;
        s0 = o1.z*o1.z; prefA[6] = prefA[5] + s0;
        s0 = o1.w*o1.w; prefA[7] = prefA[6] + s0;
        s0 = g0.x*g0.x; prefB[0] = s0;
        s0 = g0.y*g0.y; prefB[1] = prefB[0] + s0;
        s0 = g0.z*g0.z; prefB[2] = prefB[1] + s0;
        s0 = g0.w*g0.w; prefB[3] = prefB[2] + s0;
        s0 = g1.x*g1.x; prefB[4] = prefB[3] + s0;
        s0 = g1.y*g1.y; prefB[5] = prefB[4] + s0;
        s0 = g1.z*g1.z; prefB[6] = prefB[5] + s0;
        s0 = g1.w*g1.w; prefB[7] = prefB[6] + s0;
    }
    float sqA7 = o1.w * o1.w;
    float sqB7 = g1.w * g1.w;

    // ---- interleaved wave scans (2x ILP) ----
    float tsA = prefA[EPT - 1], tsB = prefB[EPT - 1];
    float wsA = tsA, wsB = tsB;
#pragma unroll
    for (int off = 1; off < 64; off <<= 1) {
        float uA = __shfl_up(wsA, off);
        float uB = __shfl_up(wsB, off);
        if (lane >= off) { wsA += uA; wsB += uB; }
    }
    if (lane == 63) { sWSA[wid] = wsA; sWSB[wid] = wsB; }
    if (tid == 0)       { sSqA[0] = prefA[0]; sSqB[0] = prefB[0]; }
    if (tid == NTH - 1) { sSqA[1] = sqA7;     sSqB[1] = sqB7; }
    __syncthreads();                                            // B1

    float exclA = wsA - tsA, exclB = wsB - tsB;
    if (wid > 0) { exclA += sWSA[0]; exclB += sWSB[0]; }
    if (wid > 1) { exclA += sWSA[1]; exclB += sWSB[1]; }
    if (wid > 2) { exclA += sWSA[2]; exclB += sWSB[2]; }
    float totA = sWSA[0] + sWSA[1] + sWSA[2] + sWSA[3];
    float totB = sWSB[0] + sWSB[1] + sWSB[2] + sWSB[3];
    float sq0A = sSqA[0], sq0B = sSqB[0];
    float invSA = 1.0f / (half_dt * (2.0f * totA - sSqA[1] - sq0A));
    float invSB = 1.0f / (half_dt * (2.0f * totB - sSqB[1] - sq0B));

    // boundary cdf handoff: c at j = base+7
    {
        float c7 = half_dt * ((exclA + prefA[6]) + (exclA + prefA[7]) - sq0A) * invSA;
        sCB[tid] = c7;
    }
    __syncthreads();                                            // B2

    // ---- inverse-CDF by forward scatter: j claims p_k in (c_{j-1}, c_j] ----
    {
        float cm = (tid == 0) ? -1.0f : sCB[tid - 1];
        float Pm = exclA;
#pragma unroll
        for (int e = 0; e < EPT; ++e) {
            int j = base + e;
            float Pj = exclA + prefA[e];
            float cc = (j == 0) ? 0.0f : half_dt * (Pm + Pj - sq0A) * invSA;
            int kLo = (int)floorf(cm * inv_h) + 1;
            int kHi = (int)floorf(cc * inv_h);
            if (kLo < 0) kLo = 0;
            if (j == NT - 1) kHi = NP - 1;          // guarantee k=1023 coverage
            else if (kHi > NP - 1) kHi = NP - 1;
            float qv = (float)j * dt;
            for (int k = kLo; k <= kHi; ++k) sQM[k].x = qv;
            cm = cc;
            Pm = Pj;
        }
    }
    __syncthreads();                                            // B3

    // ---- rhs (zero-padded) ----
#pragma unroll
    for (int kk = 0; kk < PPT; ++kk) {
        int i = tid + kk * NTH;
        if (i < MSZ)
            sRp[KT + i] = 6.0f * (sQM[i].x - 2.0f * sQM[i + 1].x + sQM[i + 2].x) * inv_h2;
    }
    __syncthreads();                                            // B4

    // ---- tridiagonal solve: constant-tap conv + redundant boundary images ----
    {
        const float Cg = 0.28867513459481288f; // 1/(2*sqrt(3))
        const float CP[KT + 1] = {
            1.0f, -0.26794919243112270f, 0.071796769724490830f,
            -0.019237886466840586f, 0.0051547761428899979f,
            -0.0013812184239975285f, 0.00037009627398250260f };
#pragma unroll
        for (int kk = 0; kk < PPT; ++kk) {
            int i = tid + kk * NTH;
            if (i < MSZ) {
                float acc = 0.0f;
#pragma unroll
                for (int d = -KT; d <= KT; ++d) {
                    int ad = d < 0 ? -d : d;
                    acc += CP[ad] * sRp[KT + i + d];
                }
                if (i + 1 < IMGW) {
                    float t1 = 0.0f;
#pragma unroll
                    for (int k2 = 0; k2 < IMGW - 1; ++k2) t1 += sPow[k2 + 1] * sRp[KT + k2];
                    acc -= sPow[i + 1] * t1;
                }
                if (MSZ - i < IMGW) {
                    float t2 = 0.0f;
#pragma unroll
                    for (int k2 = MSZ - IMGW + 1; k2 < MSZ; ++k2) t2 += sPow[MSZ - k2] * sRp[KT + k2];
                    acc -= sPow[MSZ - i] * t2;
                }
                sQM[i + 1].y = Cg * acc;
            }
        }
    }
    if (tid == 0) { sQM[0].y = 0.0f; sQM[NP - 1].y = 0.0f; }
    __syncthreads();                                            // B5

    // ---- Phase B: F in registers, spline eval, integrate ----
    float local = 0.0f;
    {
        float Pm = exclB;
#pragma unroll
        for (int e = 0; e < EPT; ++e) {
            int j = base + e;
            float Pj = exclB + prefB[e];
            float Fj = (j == 0) ? 0.0f : half_dt * (Pm + Pj - sq0B) * invSB;
            float sqe = (e == 0) ? prefB[0] : (prefB[e] - prefB[e - 1]);
            float ft = sqe * invSB;
            int k = (int)(Fj * inv_h);
            if (k < 0) k = 0;
            if (k > NP - 2) k = NP - 2;
            float s = Fj - (float)k * h;
            float2 qm0 = sQM[k];
            float2 qm1 = sQM[k + 1];
            float bco = (qm1.x - qm0.x) * inv_h - h * (2.0f * qm0.y + qm1.y) * (1.0f / 6.0f);
            float cco = 0.5f * qm0.y;
            float dco = (qm1.y - qm0.y) * (inv_h * (1.0f / 6.0f));
            float od  = qm0.x + s * (bco + s * (cco + s * dco));
            float tj  = (float)j * dt;
            float dd  = tj - od;
            float w   = (j == 0 || j == NT - 1) ? half_dt : dt;
            local += dd * dd * ft * w;
            Pm = Pj;
        }
    }

#pragma unroll
    for (int off = 32; off > 0; off >>= 1) local += __shfl_down(local, off);
    if (lane == 0) sRed[wid] = local;
    __syncthreads();                                            // B6
    if (tid == 0) atomicAdd(out, sRed[0] + sRed[1] + sRed[2] + sRed[3]);
}

extern "C" void kernel_launch(void* const* d_in, const int* in_sizes, int n_in,
                              void* d_out, int out_size, void* d_ws, size_t ws_size,
                              hipStream_t stream) {
    const float* f   = (const float*)d_in[0];
    const float* obs = (const float*)d_in[1];
    float* out = (float*)d_out;

    hipMemsetAsync(out, 0, sizeof(float), stream);
    w2loss_kernel<<<NBATCH, NTH, 0, stream>>>(f, obs, out);
}

// Round 4
// 27.779 us; speedup vs baseline: 4.0808x; 2.4319x over previous
//
#include <hip/hip_runtime.h>

#define NBATCH 4096
#define NT 2048
#define NP 1024
#define NTH 256
#define EPT 8   // NT elements per thread
#define PPT 4   // NP items per thread
#define MSZ 1022          // interior system size (NP-2)
#define KT 6              // conv half-width: |rho|^7 ~ 1e-4, scaled by h^2/6 -> ~1e-10 in spline
#define IMGW 14           // boundary image reach

__global__ __launch_bounds__(NTH, 8) void w2loss_kernel(
    const float* __restrict__ f,
    const float* __restrict__ obs,
    float* __restrict__ partial)
{
    __shared__ float2 sQM[NP];           // .x = q_k, .y = M_k
    __shared__ float  sRp[MSZ + 2 * KT]; // zero-padded rhs
    __shared__ float  sCB[NTH];          // per-thread boundary cdf (c at j=base+7)
    __shared__ float  sPow[IMGW];        // rho^d
    __shared__ float  sWSA[4], sWSB[4];
    __shared__ float  sSqA[2], sSqB[2];
    __shared__ float  sRed[4];

    const int tid  = threadIdx.x;
    const int lane = tid & 63;
    const int wid  = tid >> 6;
    const int b    = blockIdx.x;
    const int base = tid * EPT;

    const float dt      = 0.001f;
    const float half_dt = 0.0005f;
    const float h       = 0.00097751710654936461f;  // 1/1023
    const float inv_h   = 1023.0f;
    const float inv_h2  = 1046529.0f;               // 1023^2

    const float* orow = obs + (size_t)b * NT;
    const float* frow = f   + (size_t)b * NT;
    float4 o0 = *reinterpret_cast<const float4*>(orow + base);
    float4 o1 = *reinterpret_cast<const float4*>(orow + base + 4);
    float4 g0 = *reinterpret_cast<const float4*>(frow + base);
    float4 g1 = *reinterpret_cast<const float4*>(frow + base + 4);

    if (tid < IMGW) {
        const float rho = -0.26794919243112270f;
        float v = 1.0f;
        for (int i = 0; i < tid; ++i) v *= rho;
        sPow[tid] = v;
    }
    if (tid < KT) { sRp[tid] = 0.0f; sRp[KT + MSZ + tid] = 0.0f; }

    // ---- squares + per-thread prefixes for BOTH rows ----
    float prefA[EPT], prefB[EPT];
    {
        float s0;
        s0 = o0.x*o0.x; prefA[0] = s0;
        s0 = o0.y*o0.y; prefA[1] = prefA[0] + s0;
        s0 = o0.z*o0.z; prefA[2] = prefA[1] + s0;
        s0 = o0.w*o0.w; prefA[3] = prefA[2] + s0;
        s0 = o1.x*o1.x; prefA[4] = prefA[3] + s0;
        s0 = o1.y*o1.y; prefA[5] = prefA[4] + s0;
        s0 = o1.z*o1.z; prefA[6] = prefA[5] + s0;
        s0 = o1.w*o1.w; prefA[7] = prefA[6] + s0;
        s0 = g0.x*g0.x; prefB[0] = s0;
        s0 = g0.y*g0.y; prefB[1] = prefB[0] + s0;
        s0 = g0.z*g0.z; prefB[2] = prefB[1] + s0;
        s0 = g0.w*g0.w; prefB[3] = prefB[2] + s0;
        s0 = g1.x*g1.x; prefB[4] = prefB[3] + s0;
        s0 = g1.y*g1.y; prefB[5] = prefB[4] + s0;
        s0 = g1.z*g1.z; prefB[6] = prefB[5] + s0;
        s0 = g1.w*g1.w; prefB[7] = prefB[6] + s0;
    }
    float sqA7 = o1.w * o1.w;
    float sqB7 = g1.w * g1.w;

    // ---- interleaved wave scans (2x ILP) ----
    float tsA = prefA[EPT - 1], tsB = prefB[EPT - 1];
    float wsA = tsA, wsB = tsB;
#pragma unroll
    for (int off = 1; off < 64; off <<= 1) {
        float uA = __shfl_up(wsA, off);
        float uB = __shfl_up(wsB, off);
        if (lane >= off) { wsA += uA; wsB += uB; }
    }
    if (lane == 63) { sWSA[wid] = wsA; sWSB[wid] = wsB; }
    if (tid == 0)       { sSqA[0] = prefA[0]; sSqB[0] = prefB[0]; }
    if (tid == NTH - 1) { sSqA[1] = sqA7;     sSqB[1] = sqB7; }
    __syncthreads();                                            // B1

    float exclA = wsA - tsA, exclB = wsB - tsB;
    if (wid > 0) { exclA += sWSA[0]; exclB += sWSB[0]; }
    if (wid > 1) { exclA += sWSA[1]; exclB += sWSB[1]; }
    if (wid > 2) { exclA += sWSA[2]; exclB += sWSB[2]; }
    float totA = sWSA[0] + sWSA[1] + sWSA[2] + sWSA[3];
    float totB = sWSB[0] + sWSB[1] + sWSB[2] + sWSB[3];
    float sq0A = sSqA[0], sq0B = sSqB[0];
    float invSA = 1.0f / (half_dt * (2.0f * totA - sSqA[1] - sq0A));
    float invSB = 1.0f / (half_dt * (2.0f * totB - sSqB[1] - sq0B));

    // boundary cdf handoff: c at j = base+7
    {
        float c7 = half_dt * ((exclA + prefA[6]) + (exclA + prefA[7]) - sq0A) * invSA;
        sCB[tid] = c7;
    }
    __syncthreads();                                            // B2

    // ---- inverse-CDF by forward scatter: j claims p_k in (c_{j-1}, c_j] ----
    {
        float cm = (tid == 0) ? -1.0f : sCB[tid - 1];
        float Pm = exclA;
#pragma unroll
        for (int e = 0; e < EPT; ++e) {
            int j = base + e;
            float Pj = exclA + prefA[e];
            float cc = (j == 0) ? 0.0f : half_dt * (Pm + Pj - sq0A) * invSA;
            int kLo = (int)floorf(cm * inv_h) + 1;
            int kHi = (int)floorf(cc * inv_h);
            if (kLo < 0) kLo = 0;
            if (j == NT - 1) kHi = NP - 1;          // guarantee k=1023 coverage
            else if (kHi > NP - 1) kHi = NP - 1;
            float qv = (float)j * dt;
            for (int k = kLo; k <= kHi; ++k) sQM[k].x = qv;
            cm = cc;
            Pm = Pj;
        }
    }
    __syncthreads();                                            // B3

    // ---- rhs (zero-padded) ----
#pragma unroll
    for (int kk = 0; kk < PPT; ++kk) {
        int i = tid + kk * NTH;
        if (i < MSZ)
            sRp[KT + i] = 6.0f * (sQM[i].x - 2.0f * sQM[i + 1].x + sQM[i + 2].x) * inv_h2;
    }
    __syncthreads();                                            // B4

    // ---- tridiagonal solve: constant-tap conv + redundant boundary images ----
    {
        const float Cg = 0.28867513459481288f; // 1/(2*sqrt(3))
        const float CP[KT + 1] = {
            1.0f, -0.26794919243112270f, 0.071796769724490830f,
            -0.019237886466840586f, 0.0051547761428899979f,
            -0.0013812184239975285f, 0.00037009627398250260f };
#pragma unroll
        for (int kk = 0; kk < PPT; ++kk) {
            int i = tid + kk * NTH;
            if (i < MSZ) {
                float acc = 0.0f;
#pragma unroll
                for (int d = -KT; d <= KT; ++d) {
                    int ad = d < 0 ? -d : d;
                    acc += CP[ad] * sRp[KT + i + d];
                }
                if (i + 1 < IMGW) {
                    float t1 = 0.0f;
#pragma unroll
                    for (int k2 = 0; k2 < IMGW - 1; ++k2) t1 += sPow[k2 + 1] * sRp[KT + k2];
                    acc -= sPow[i + 1] * t1;
                }
                if (MSZ - i < IMGW) {
                    float t2 = 0.0f;
#pragma unroll
                    for (int k2 = MSZ - IMGW + 1; k2 < MSZ; ++k2) t2 += sPow[MSZ - k2] * sRp[KT + k2];
                    acc -= sPow[MSZ - i] * t2;
                }
                sQM[i + 1].y = Cg * acc;
            }
        }
    }
    if (tid == 0) { sQM[0].y = 0.0f; sQM[NP - 1].y = 0.0f; }
    __syncthreads();                                            // B5

    // ---- Phase B: F in registers, spline eval, integrate ----
    float local = 0.0f;
    {
        float Pm = exclB;
#pragma unroll
        for (int e = 0; e < EPT; ++e) {
            int j = base + e;
            float Pj = exclB + prefB[e];
            float Fj = (j == 0) ? 0.0f : half_dt * (Pm + Pj - sq0B) * invSB;
            float sqe = (e == 0) ? prefB[0] : (prefB[e] - prefB[e - 1]);
            float ft = sqe * invSB;
            int k = (int)(Fj * inv_h);
            if (k < 0) k = 0;
            if (k > NP - 2) k = NP - 2;
            float s = Fj - (float)k * h;
            float2 qm0 = sQM[k];
            float2 qm1 = sQM[k + 1];
            float bco = (qm1.x - qm0.x) * inv_h - h * (2.0f * qm0.y + qm1.y) * (1.0f / 6.0f);
            float cco = 0.5f * qm0.y;
            float dco = (qm1.y - qm0.y) * (inv_h * (1.0f / 6.0f));
            float od  = qm0.x + s * (bco + s * (cco + s * dco));
            float tj  = (float)j * dt;
            float dd  = tj - od;
            float w   = (j == 0 || j == NT - 1) ? half_dt : dt;
            local += dd * dd * ft * w;
            Pm = Pj;
        }
    }

#pragma unroll
    for (int off = 32; off > 0; off >>= 1) local += __shfl_down(local, off);
    if (lane == 0) sRed[wid] = local;
    __syncthreads();                                            // B6
    if (tid == 0) partial[b] = sRed[0] + sRed[1] + sRed[2] + sRed[3];
}

// fixed-order deterministic reduction of 4096 partials -> scalar
__global__ __launch_bounds__(NTH) void w2loss_reduce(
    const float* __restrict__ partial, float* __restrict__ out)
{
    __shared__ float sRed[4];
    const int tid  = threadIdx.x;
    const int lane = tid & 63;
    const int wid  = tid >> 6;
    float s = 0.0f;
#pragma unroll
    for (int i = 0; i < 16; i += 4) {
        float4 v = *reinterpret_cast<const float4*>(partial + tid * 16 + i);
        s += v.x + v.y + v.z + v.w;
    }
#pragma unroll
    for (int off = 32; off > 0; off >>= 1) s += __shfl_down(s, off);
    if (lane == 0) sRed[wid] = s;
    __syncthreads();
    if (tid == 0) out[0] = sRed[0] + sRed[1] + sRed[2] + sRed[3];
}

extern "C" void kernel_launch(void* const* d_in, const int* in_sizes, int n_in,
                              void* d_out, int out_size, void* d_ws, size_t ws_size,
                              hipStream_t stream) {
    const float* f   = (const float*)d_in[0];
    const float* obs = (const float*)d_in[1];
    float* out     = (float*)d_out;
    float* partial = (float*)d_ws;   // 4096 floats = 16 KB scratch

    w2loss_kernel<<<NBATCH, NTH, 0, stream>>>(f, obs, partial);
    w2loss_reduce<<<1, NTH, 0, stream>>>(partial, out);
}